// Round 5
// baseline (83.443 us; speedup 1.0000x reference)
//
#include <hip/hip_runtime.h>
#include <math.h>

#define TILE  512
#define BLOCK 256
#define NC    128

// ws layout: pbmin (NB*NC floats) at +0 ; stage (NC floats) at +512K ; done at +516K.

// One block per 512-point tile.
// Camera scalars: fp64 per-block (bit-matched np, R1-R4 absmax 0.0).
// Phase 1: coalesced float2 point loads, project -> SoA LDS u[512],v[512],b2[512].
// Phase 2: 16 scanners/block (quarter-waves); each = 16 lanes x 8 corners,
//   scans 32 points via float4 SoA reads (3 reads per 4 points). Quarter q
//   rotates its group index by 2q so the 4 quarters of a wave hit disjoint
//   bank groups (conflict-free). 3 VALU per (corner,point) pair -> VALU-bound.
// Tail: per-block corner minima stored coalesced to pbmin[block][*].
__global__ __launch_bounds__(BLOCK) void proj_min_kernel(
        const float* __restrict__ pnt,
        const float* __restrict__ cor,
        const float* __restrict__ cam,
        const float* __restrict__ theta,
        const float* __restrict__ vang,
        const int* __restrict__ hh,
        const int* __restrict__ ww,
        float* __restrict__ pbmin,
        unsigned* __restrict__ done,
        int n) {
    __shared__ float uu[TILE], vv[TILE], bb[TILE];
    __shared__ float red[4 * NC];
    __shared__ float sc[12];

    const int tid  = threadIdx.x;
    const int base = blockIdx.x * TILE;

    if (blockIdx.x == 0 && tid == 0) *done = 0u;   // reset for colmin_sum

    // ---- coalesced point prefetch ----
    const int i0 = base + 2 * tid;
    float p0x = 0.f, p0y = 0.f, p0z = 0.f;
    float p1x = 0.f, p1y = 0.f, p1z = 0.f;
    const bool v0 = (i0 < n), v1 = (i0 + 1 < n);
    if (v1) {
        const float2* q = (const float2*)(pnt + 3 * i0);
        float2 a = q[0], b = q[1], c = q[2];        // x0 y0 | z0 x1 | y1 z1
        p0x = a.x; p0y = a.y; p0z = b.x;
        p1x = b.y; p1y = c.x; p1z = c.y;
    } else if (v0) {
        p0x = pnt[3 * i0]; p0y = pnt[3 * i0 + 1]; p0z = pnt[3 * i0 + 2];
    }

    // ---- fp64 camera scalars, once per block ----
    if (tid == 0) {
        const double D2R = 0.017453292519943295;
        double a = (double)theta[0] * D2R;
        double b = (double)theta[1] * D2R;
        double c = (double)theta[2] * D2R;
        double sa = sin(a), ca = cos(a);
        double sb = sin(b), cb = cos(b);
        double sc_ = sin(c), cc = cos(c);
        double H = (double)hh[0], W = (double)ww[0];
        double fd = -H / (2.0 * tan((double)vang[0] * 0.5 * D2R));
        sc[0] = (float)(cc * cb);
        sc[1] = (float)(cc * sb * sa - sc_ * ca);
        sc[2] = (float)(cc * sb * ca + sc_ * sa);
        sc[3] = (float)(sc_ * cb);
        sc[4] = (float)(sc_ * sb * sa + cc * ca);
        sc[5] = (float)(sc_ * sb * ca - cc * sa);
        sc[6] = (float)(-sb);
        sc[7] = (float)(cb * sa);
        sc[8] = (float)(cb * ca);
        sc[9]  = (float)fd;               // f
        sc[10] = (float)(W * 0.5 - 0.5);  // cx
        sc[11] = (float)(H * 0.5 + 0.5);  // H - cy (v-flip offset)
    }
    __syncthreads();

    const float r00 = sc[0], r01 = sc[1], r02 = sc[2];
    const float r10 = sc[3], r11 = sc[4], r12 = sc[5];
    const float r20 = sc[6], r21 = sc[7], r22 = sc[8];
    const float f = sc[9], cx = sc[10], cyv = sc[11];
    const float c0 = cam[0], c1 = cam[1], c2 = cam[2];

    {   // project owned points -> SoA LDS (float2 writes, 2-way = free)
        float u0 = 0.f, w0 = 0.f, b20 = 3.0e38f;
        float u1 = 0.f, w1 = 0.f, b21 = 3.0e38f;
        if (v0) {
            float tx = p0x - c0, ty = p0y - c1, tz = p0z - c2;
            float x = fmaf(r00, tx, fmaf(r01, ty, r02 * tz));
            float y = fmaf(r10, tx, fmaf(r11, ty, r12 * tz));
            float z = fmaf(r20, tx, fmaf(r21, ty, r22 * tz));
            float xz = x / z, yz = y / z;            // true divide, matches np
            u0 = fmaf(f, xz, cx);
            w0 = fmaf(-f, yz, cyv);
            b20 = fmaf(u0, u0, w0 * w0);
        }
        if (v1) {
            float tx = p1x - c0, ty = p1y - c1, tz = p1z - c2;
            float x = fmaf(r00, tx, fmaf(r01, ty, r02 * tz));
            float y = fmaf(r10, tx, fmaf(r11, ty, r12 * tz));
            float z = fmaf(r20, tx, fmaf(r21, ty, r22 * tz));
            float xz = x / z, yz = y / z;
            u1 = fmaf(f, xz, cx);
            w1 = fmaf(-f, yz, cyv);
            b21 = fmaf(u1, u1, w1 * w1);
        }
        *(float2*)(uu + 2 * tid) = make_float2(u0, u1);
        *(float2*)(vv + 2 * tid) = make_float2(w0, w1);
        *(float2*)(bb + 2 * tid) = make_float2(b20, b21);
    }
    __syncthreads();

    const int lane = tid & 63;
    const int w    = tid >> 6;        // wave 0..3
    const int q    = lane >> 4;       // quarter-wave 0..3
    const int sl   = lane & 15;       // sublane 0..15
    const int cb   = sl << 3;         // this lane's 8 corners

    float bx[8], by[8], m[8];
    #pragma unroll
    for (int k = 0; k < 8; ++k) {
        bx[k] = -2.f * cor[2 * (cb + k)];
        by[k] = -2.f * cor[2 * (cb + k) + 1];
        m[k]  = 3.4e38f;
    }

    const float4* uu4 = (const float4*)uu;
    const float4* vv4 = (const float4*)vv;
    const float4* bb4 = (const float4*)bb;
    const int g0 = (w * 4 + q) * 8;   // this scanner's 8 point-groups

    #pragma unroll
    for (int j = 0; j < 8; ++j) {
        const int gi = g0 + ((j + 2 * q) & 7);   // bank-swizzled group
        float4 u4 = uu4[gi];
        float4 v4 = vv4[gi];
        float4 b4 = bb4[gi];
        #pragma unroll
        for (int k = 0; k < 8; ++k) {
            m[k] = fminf(m[k], fmaf(bx[k], u4.x, fmaf(by[k], v4.x, b4.x)));
            m[k] = fminf(m[k], fmaf(bx[k], u4.y, fmaf(by[k], v4.y, b4.y)));
            m[k] = fminf(m[k], fmaf(bx[k], u4.z, fmaf(by[k], v4.z, b4.z)));
            m[k] = fminf(m[k], fmaf(bx[k], u4.w, fmaf(by[k], v4.w, b4.w)));
        }
    }

    // fold quarters within the wave
    #pragma unroll
    for (int k = 0; k < 8; ++k)
        m[k] = fminf(m[k], __shfl_xor(m[k], 16));
    #pragma unroll
    for (int k = 0; k < 8; ++k)
        m[k] = fminf(m[k], __shfl_xor(m[k], 32));
    if (lane < 16) {
        #pragma unroll
        for (int k = 0; k < 8; k += 4)
            *(float4*)(red + w * NC + cb + k) =
                make_float4(m[k], m[k + 1], m[k + 2], m[k + 3]);
    }
    __syncthreads();

    if (tid < NC) {   // cross-wave min, coalesced block-major store
        float mm = fminf(fminf(red[tid], red[NC + tid]),
                         fminf(red[2 * NC + tid], red[3 * NC + tid]));
        pbmin[blockIdx.x * NC + tid] = mm;
    }
}

// One block per corner, 64 threads: column min over pbmin[*][c], +||a||^2,
// release-store to stage[c]; the LAST block (agent-scope counter) does the
// fp64 final sum and writes out[0]. Zero same-address data atomics.
__global__ __launch_bounds__(64) void colmin_sum_kernel(
        const float* __restrict__ pbmin,
        const float* __restrict__ cor,
        float* __restrict__ stage,
        unsigned* __restrict__ done,
        float* __restrict__ out, int NB) {
    const int c = blockIdx.x;
    const int t = threadIdx.x;
    float m = 3.4e38f;
    for (int r = t; r < NB; r += 64)
        m = fminf(m, pbmin[r * NC + c]);
    #pragma unroll
    for (int off = 32; off > 0; off >>= 1)
        m = fminf(m, __shfl_down(m, off));

    __shared__ int last;
    if (t == 0) {
        float ax = cor[2 * c], ay = cor[2 * c + 1];
        __hip_atomic_store(&stage[c], m + fmaf(ax, ax, ay * ay),
                           __ATOMIC_RELEASE, __HIP_MEMORY_SCOPE_AGENT);
        unsigned old = __hip_atomic_fetch_add(done, 1u, __ATOMIC_ACQ_REL,
                                              __HIP_MEMORY_SCOPE_AGENT);
        last = (old == NC - 1) ? 1 : 0;
    }
    __syncthreads();
    if (last) {
        double s = (double)__hip_atomic_load(&stage[t], __ATOMIC_ACQUIRE,
                                             __HIP_MEMORY_SCOPE_AGENT)
                 + (double)__hip_atomic_load(&stage[t + 64], __ATOMIC_ACQUIRE,
                                             __HIP_MEMORY_SCOPE_AGENT);
        #pragma unroll
        for (int off = 32; off > 0; off >>= 1)
            s += __shfl_down(s, off);
        if (t == 0) out[0] = (float)s;
    }
}

extern "C" void kernel_launch(void* const* d_in, const int* in_sizes, int n_in,
                              void* d_out, int out_size, void* d_ws, size_t ws_size,
                              hipStream_t stream) {
    const float* pnt   = (const float*)d_in[0];  // (400000,3)
    const float* cor   = (const float*)d_in[1];  // (128,2)
    const float* cam   = (const float*)d_in[2];  // (3,)
    const float* theta = (const float*)d_in[3];  // (3,)
    const float* vang  = (const float*)d_in[4];  // (1,)
    const int*   hh    = (const int*)d_in[5];    // scalar int
    const int*   ww    = (const int*)d_in[6];    // scalar int

    int n  = in_sizes[0] / 3;
    int NB = (n + TILE - 1) / TILE;

    float*    pbmin = (float*)d_ws;                          // NB*NC floats
    float*    stage = (float*)((char*)d_ws + 512 * 1024);    // NC floats
    unsigned* done  = (unsigned*)((char*)d_ws + 516 * 1024); // 1 counter

    proj_min_kernel<<<NB, BLOCK, 0, stream>>>(pnt, cor, cam, theta, vang,
                                              hh, ww, pbmin, done, n);
    colmin_sum_kernel<<<NC, 64, 0, stream>>>(pbmin, cor, stage, done,
                                             (float*)d_out, NB);
}

// Round 6
// 81.291 us; speedup vs baseline: 1.0265x; 1.0265x over previous
//
#include <hip/hip_runtime.h>
#include <math.h>

#define TILE  512
#define BLOCK 256
#define NC    128

// ws layout: pbmin (NB*NC floats) at +0 ; stage (NC floats) at +512K ; done at +516K.

// One block per 512-point tile. (R4's measured-fastest proj, unchanged except
// the done-counter reset.)
// Camera scalars: fp64 per-block by thread 0 (bit-matched np, absmax 0.0 R1-R5).
// Phase 1: coalesced float2 point loads -> project -> LDS (u, vflip, ||b||^2, 0).
// Phase 2: lane owns 4 corners; the wave's two 32-lane halves scan disjoint
//   64-point ranges (2-way LDS aliasing = free). 3 VALU per (corner,point).
// Tail: per-block corner minima stored coalesced to pbmin[block][*].
__global__ __launch_bounds__(BLOCK) void proj_min_kernel(
        const float* __restrict__ pnt,
        const float* __restrict__ cor,
        const float* __restrict__ cam,
        const float* __restrict__ theta,
        const float* __restrict__ vang,
        const int* __restrict__ hh,
        const int* __restrict__ ww,
        float* __restrict__ pbmin,
        unsigned* __restrict__ done,
        int n) {
    __shared__ float4 uvb[TILE];
    __shared__ float red[4 * NC];
    __shared__ float sc[12];

    const int tid  = threadIdx.x;
    const int base = blockIdx.x * TILE;

    if (blockIdx.x == 0 && tid == 0) *done = 0u;   // reset for colmin_sum

    // ---- coalesced point prefetch (issued before trig to hide HBM latency) ----
    const int i0 = base + 2 * tid;
    float p0x = 0.f, p0y = 0.f, p0z = 0.f;
    float p1x = 0.f, p1y = 0.f, p1z = 0.f;
    const bool v0 = (i0 < n), v1 = (i0 + 1 < n);
    if (v1) {
        const float2* q = (const float2*)(pnt + 3 * i0);
        float2 a = q[0], b = q[1], c = q[2];        // x0 y0 | z0 x1 | y1 z1
        p0x = a.x; p0y = a.y; p0z = b.x;
        p1x = b.y; p1y = c.x; p1z = c.y;
    } else if (v0) {
        p0x = pnt[3 * i0]; p0y = pnt[3 * i0 + 1]; p0z = pnt[3 * i0 + 2];
    }

    // ---- fp64 camera scalars, once per block ----
    if (tid == 0) {
        const double D2R = 0.017453292519943295;
        double a = (double)theta[0] * D2R;
        double b = (double)theta[1] * D2R;
        double c = (double)theta[2] * D2R;
        double sa = sin(a), ca = cos(a);
        double sb = sin(b), cb = cos(b);
        double sc_ = sin(c), cc = cos(c);
        double H = (double)hh[0], W = (double)ww[0];
        double fd = -H / (2.0 * tan((double)vang[0] * 0.5 * D2R));
        sc[0] = (float)(cc * cb);
        sc[1] = (float)(cc * sb * sa - sc_ * ca);
        sc[2] = (float)(cc * sb * ca + sc_ * sa);
        sc[3] = (float)(sc_ * cb);
        sc[4] = (float)(sc_ * sb * sa + cc * ca);
        sc[5] = (float)(sc_ * sb * ca - cc * sa);
        sc[6] = (float)(-sb);
        sc[7] = (float)(cb * sa);
        sc[8] = (float)(cb * ca);
        sc[9]  = (float)fd;               // f
        sc[10] = (float)(W * 0.5 - 0.5);  // cx
        sc[11] = (float)(H * 0.5 + 0.5);  // H - cy (v-flip offset)
    }
    __syncthreads();

    const float r00 = sc[0], r01 = sc[1], r02 = sc[2];
    const float r10 = sc[3], r11 = sc[4], r12 = sc[5];
    const float r20 = sc[6], r21 = sc[7], r22 = sc[8];
    const float f = sc[9], cx = sc[10], cyv = sc[11];
    const float c0 = cam[0], c1 = cam[1], c2 = cam[2];

    {   // project the two owned points -> LDS
        float u0 = 0.f, w0 = 0.f, b20 = 3.0e38f;
        float u1 = 0.f, w1 = 0.f, b21 = 3.0e38f;
        if (v0) {
            float tx = p0x - c0, ty = p0y - c1, tz = p0z - c2;
            float x = fmaf(r00, tx, fmaf(r01, ty, r02 * tz));
            float y = fmaf(r10, tx, fmaf(r11, ty, r12 * tz));
            float z = fmaf(r20, tx, fmaf(r21, ty, r22 * tz));
            float xz = x / z, yz = y / z;            // true divide, matches np
            u0 = fmaf(f, xz, cx);
            w0 = fmaf(-f, yz, cyv);
            b20 = fmaf(u0, u0, w0 * w0);
        }
        if (v1) {
            float tx = p1x - c0, ty = p1y - c1, tz = p1z - c2;
            float x = fmaf(r00, tx, fmaf(r01, ty, r02 * tz));
            float y = fmaf(r10, tx, fmaf(r11, ty, r12 * tz));
            float z = fmaf(r20, tx, fmaf(r21, ty, r22 * tz));
            float xz = x / z, yz = y / z;
            u1 = fmaf(f, xz, cx);
            w1 = fmaf(-f, yz, cyv);
            b21 = fmaf(u1, u1, w1 * w1);
        }
        uvb[2 * tid]     = make_float4(u0, w0, b20, 0.f);
        uvb[2 * tid + 1] = make_float4(u1, w1, b21, 0.f);
    }
    __syncthreads();

    const int lane = tid & 63;
    const int w    = tid >> 6;        // wave id
    const int h    = lane >> 5;       // half-wave subrange
    const int sl   = lane & 31;
    const int cb   = sl << 2;         // this lane's 4 corners

    float bx[4], by[4], m[4];
    #pragma unroll
    for (int k = 0; k < 4; ++k) {
        bx[k] = -2.f * cor[2 * (cb + k)];
        by[k] = -2.f * cor[2 * (cb + k) + 1];
        m[k]  = 3.4e38f;
    }

    const float4* p = &uvb[(w << 7) + (h << 6)];
    #pragma unroll 8
    for (int j = 0; j < 64; ++j) {
        float4 q = p[j];
        #pragma unroll
        for (int k = 0; k < 4; ++k)
            m[k] = fminf(m[k], fmaf(bx[k], q.x, fmaf(by[k], q.y, q.z)));
    }

    #pragma unroll
    for (int k = 0; k < 4; ++k)
        m[k] = fminf(m[k], __shfl_xor(m[k], 32));
    if (lane < 32) {
        #pragma unroll
        for (int k = 0; k < 4; ++k)
            red[w * NC + cb + k] = m[k];
    }
    __syncthreads();

    if (tid < NC) {
        float mm = fminf(fminf(red[tid], red[NC + tid]),
                         fminf(red[2 * NC + tid], red[3 * NC + tid]));
        pbmin[blockIdx.x * NC + tid] = mm;
    }
}

// One block per corner, 64 threads: column min over pbmin[*][c], +||a||^2,
// release-store to stage[c]; the LAST block (agent-scope counter) does the
// fp64 final sum and writes out[0]. (Proven correct in R5.)
__global__ __launch_bounds__(64) void colmin_sum_kernel(
        const float* __restrict__ pbmin,
        const float* __restrict__ cor,
        float* __restrict__ stage,
        unsigned* __restrict__ done,
        float* __restrict__ out, int NB) {
    const int c = blockIdx.x;
    const int t = threadIdx.x;
    float m = 3.4e38f;
    for (int r = t; r < NB; r += 64)
        m = fminf(m, pbmin[r * NC + c]);
    #pragma unroll
    for (int off = 32; off > 0; off >>= 1)
        m = fminf(m, __shfl_down(m, off));

    __shared__ int last;
    if (t == 0) {
        float ax = cor[2 * c], ay = cor[2 * c + 1];
        __hip_atomic_store(&stage[c], m + fmaf(ax, ax, ay * ay),
                           __ATOMIC_RELEASE, __HIP_MEMORY_SCOPE_AGENT);
        unsigned old = __hip_atomic_fetch_add(done, 1u, __ATOMIC_ACQ_REL,
                                              __HIP_MEMORY_SCOPE_AGENT);
        last = (old == NC - 1) ? 1 : 0;
    }
    __syncthreads();
    if (last) {
        double s = (double)__hip_atomic_load(&stage[t], __ATOMIC_ACQUIRE,
                                             __HIP_MEMORY_SCOPE_AGENT)
                 + (double)__hip_atomic_load(&stage[t + 64], __ATOMIC_ACQUIRE,
                                             __HIP_MEMORY_SCOPE_AGENT);
        #pragma unroll
        for (int off = 32; off > 0; off >>= 1)
            s += __shfl_down(s, off);
        if (t == 0) out[0] = (float)s;
    }
}

extern "C" void kernel_launch(void* const* d_in, const int* in_sizes, int n_in,
                              void* d_out, int out_size, void* d_ws, size_t ws_size,
                              hipStream_t stream) {
    const float* pnt   = (const float*)d_in[0];  // (400000,3)
    const float* cor   = (const float*)d_in[1];  // (128,2)
    const float* cam   = (const float*)d_in[2];  // (3,)
    const float* theta = (const float*)d_in[3];  // (3,)
    const float* vang  = (const float*)d_in[4];  // (1,)
    const int*   hh    = (const int*)d_in[5];    // scalar int
    const int*   ww    = (const int*)d_in[6];    // scalar int

    int n  = in_sizes[0] / 3;
    int NB = (n + TILE - 1) / TILE;

    float*    pbmin = (float*)d_ws;                          // NB*NC floats
    float*    stage = (float*)((char*)d_ws + 512 * 1024);    // NC floats
    unsigned* done  = (unsigned*)((char*)d_ws + 516 * 1024); // 1 counter

    proj_min_kernel<<<NB, BLOCK, 0, stream>>>(pnt, cor, cam, theta, vang,
                                              hh, ww, pbmin, done, n);
    colmin_sum_kernel<<<NC, 64, 0, stream>>>(pbmin, cor, stage, done,
                                             (float*)d_out, NB);
}